// Round 3
// baseline (450.043 us; speedup 1.0000x reference)
//
#include <hip/hip_runtime.h>
#include <hip/hip_bf16.h>
#include <stdint.h>

// Problem constants: features 8192x128 f32, prototypes 10101x128 f32,
// path_idx 10000x3 i32, weights [0,1,1]/2 -> out[n,l] = 0.5*(F[n].P[idx1] + F[n].P[idx2])
#define M_DIM      8192
#define K_DIM      128
#define NUM_LEAVES 10000
#define N_PAD      10112   // 79 * 128, zero-padded Q rows
#define TILES      79      // column tiles of 128 leaves
#define ROWS_PB    16      // output rows per block; 512 blocks cover 8192 rows

typedef __attribute__((ext_vector_type(8))) short bf16x8;
typedef __attribute__((ext_vector_type(4))) float f32x4;

static __device__ __forceinline__ unsigned short f2bf(float f) {
    union { float f; uint32_t u; } v; v.f = f;
    uint32_t u = v.u;
    u += 0x7FFFu + ((u >> 16) & 1u);   // round-to-nearest-even
    return (unsigned short)(u >> 16);
}

// fp32 features -> bf16, one float4 per thread
__global__ void prep_features(const float* __restrict__ F, unsigned short* __restrict__ Fb) {
    int t = blockIdx.x * blockDim.x + threadIdx.x;
    float4 v = ((const float4*)F)[t];
    ushort4 o;
    o.x = f2bf(v.x); o.y = f2bf(v.y); o.z = f2bf(v.z); o.w = f2bf(v.w);
    ((ushort4*)Fb)[t] = o;
}

// Q[l][k] = 0.5*(P[idx[l,1]][k] + P[idx[l,2]][k]) as bf16; rows >= NUM_LEAVES zeroed.
__global__ void prep_q(const float* __restrict__ P, const int* __restrict__ idx,
                       unsigned short* __restrict__ Qb) {
    int t = blockIdx.x * blockDim.x + threadIdx.x;
    int l = t >> 5;
    int c = (t & 31) << 2;
    ushort4 o;
    if (l < NUM_LEAVES) {
        int i1 = idx[l * 3 + 1];
        int i2 = idx[l * 3 + 2];
        float4 a = *(const float4*)&P[(size_t)i1 * K_DIM + c];
        float4 b = *(const float4*)&P[(size_t)i2 * K_DIM + c];
        o.x = f2bf(0.5f * (a.x + b.x));
        o.y = f2bf(0.5f * (a.y + b.y));
        o.z = f2bf(0.5f * (a.z + b.z));
        o.w = f2bf(0.5f * (a.w + b.w));
    } else {
        o.x = 0; o.y = 0; o.z = 0; o.w = 0;
    }
    *(ushort4*)&Qb[(size_t)l * K_DIM + c] = o;
}

// Row-streaming GEMM: block = 16 full output rows (contiguous 640 KB of out),
// swept over 79 column tiles. Wave w owns a 32-leaf column lane (wn = w*32).
// A (16x128) lives in registers; B fragments are loaded register-direct from
// L2-resident Qb with a 1-tile prefetch. Barrier-free: the f32 transpose buffer
// is per-wave-private LDS with an XOR chunk swizzle (uniform 8-lane/bank-group).
__device__ __forceinline__ void tile_step(
    const bf16x8 (&bq)[8], const bf16x8 (&a4)[4],
    float* __restrict__ Tw, float* __restrict__ out,
    int t, int R0, int wn, int l15, int quad, int lane)
{
    f32x4 acc[2] = {};
#pragma unroll
    for (int kt = 0; kt < 4; ++kt) {
#pragma unroll
        for (int ni = 0; ni < 2; ++ni)
            acc[ni] = __builtin_amdgcn_mfma_f32_16x16x32_bf16(
                bq[ni * 4 + kt], a4[kt], acc[ni], 0, 0, 0);
    }
    // acc[ni]: out row (R0 + l15), cols t*128 + wn + ni*16 + quad*4 + 0..3.
    // Stage into wave-private T (16 rows x 8 chunks of 16B), chunk ^= row&7.
#pragma unroll
    for (int ni = 0; ni < 2; ++ni) {
        int chunk = (ni * 4 + quad) ^ (l15 & 7);
        *(f32x4*)&Tw[l15 * 32 + chunk * 4] = acc[ni];
    }
    // Read back row-major: 8 rows x 128 B contiguous per store instruction.
    const int h3 = lane >> 3;
    const int c8 = lane & 7;
    const int rchunk = c8 ^ h3;          // (row&7) == h3
    const int c = t * 128 + wn + c8 * 4; // global leaf col of this lane's 16B
#pragma unroll
    for (int it = 0; it < 2; ++it) {
        int r = it * 8 + h3;
        f32x4 v = *(const f32x4*)&Tw[r * 32 + rchunk * 4];
        if (c < NUM_LEAVES) {            // c%4==0 and 10000%4==0 -> whole float4
            *(f32x4*)&out[(size_t)(R0 + r) * NUM_LEAVES + c] = v;
        }
    }
}

#define LOADB(dst, t)                                                              \
    do {                                                                           \
        _Pragma("unroll")                                                          \
        for (int ni = 0; ni < 2; ++ni) {                                           \
            _Pragma("unroll")                                                      \
            for (int kt = 0; kt < 4; ++kt)                                         \
                dst[ni * 4 + kt] = *(const bf16x8*)&qbase[(size_t)(t) * 16384 +    \
                                                          ni * 2048 + kt * 32];    \
        }                                                                          \
    } while (0)

__global__ __launch_bounds__(256, 4) void gemm_rows(
    const unsigned short* __restrict__ Fb,
    const unsigned short* __restrict__ Qb,
    float* __restrict__ out)
{
    __shared__ float T[4][16 * 32];      // 2 KB per wave, wave-private

    const int tid  = threadIdx.x;
    const int lane = tid & 63;
    const int w    = tid >> 6;
    const int l15  = lane & 15;
    const int quad = lane >> 4;
    const int wn   = w * 32;
    const int R0   = blockIdx.x * ROWS_PB;
    float* Tw = &T[w][0];

    // A fragments: rows R0..R0+15, all K=128, hoisted to registers once.
    bf16x8 a4[4];
#pragma unroll
    for (int kt = 0; kt < 4; ++kt)
        a4[kt] = *(const bf16x8*)&Fb[(size_t)(R0 + l15) * K_DIM + kt * 32 + quad * 8];

    // Per-lane B base: row (wn + l15), K-chunk quad.
    const unsigned short* qbase = Qb + (size_t)(wn + l15) * K_DIM + quad * 8;

    bf16x8 bA[8], bB[8];
    LOADB(bA, 0);
#pragma unroll 1
    for (int it = 0; it < 39; ++it) {
        const int t0 = it * 2;
        LOADB(bB, t0 + 1);
        tile_step(bA, a4, Tw, out, t0, R0, wn, l15, quad, lane);
        LOADB(bA, t0 + 2);
        tile_step(bB, a4, Tw, out, t0 + 1, R0, wn, l15, quad, lane);
    }
    tile_step(bA, a4, Tw, out, 78, R0, wn, l15, quad, lane);
}

extern "C" void kernel_launch(void* const* d_in, const int* in_sizes, int n_in,
                              void* d_out, int out_size, void* d_ws, size_t ws_size,
                              hipStream_t stream) {
    const float* F  = (const float*)d_in[0];   // 8192*128 f32
    const float* P  = (const float*)d_in[1];   // 10101*128 f32
    const int* idx  = (const int*)d_in[2];     // 10000*3 i32
    float* out      = (float*)d_out;           // 8192*10000 f32

    unsigned short* Fb = (unsigned short*)d_ws;            // 8192*128 bf16 (2 MB)
    unsigned short* Qb = Fb + (size_t)M_DIM * K_DIM;       // 10112*128 bf16 (2.6 MB)

    prep_features<<<(M_DIM * K_DIM / 4) / 256, 256, 0, stream>>>(F, Fb);
    prep_q<<<(N_PAD * 32) / 256, 256, 0, stream>>>(P, idx, Qb);
    gemm_rows<<<M_DIM / ROWS_PB, 256, 0, stream>>>(Fb, Qb, out);
}

// Round 5
// 380.042 us; speedup vs baseline: 1.1842x; 1.1842x over previous
//
#include <hip/hip_runtime.h>
#include <hip/hip_bf16.h>
#include <stdint.h>

// Problem constants: features 8192x128 f32, prototypes 10101x128 f32,
// path_idx 10000x3 i32, weights [0,1,1]/2 -> out[n,l] = 0.5*(F[n].P[idx1] + F[n].P[idx2])
#define M_DIM      8192
#define K_DIM      128
#define NUM_LEAVES 10000
#define N_PAD      10112   // 79 * 128, zero-padded Q rows
#define NT         79      // N tiles of 128
#define MT         64      // M tiles of 128
#define NWG        (NT * MT)   // 5056 = 8 * 632, divisible by 8 XCDs
#define LDS_STRIDE 136     // 128 + 8 bf16 pad (16B) -> b128 reads land on rotating banks
#define T_STRIDE   132     // f32 transpose-staging stride (conflict-minimal b128)

typedef __attribute__((ext_vector_type(8))) short bf16x8;
typedef __attribute__((ext_vector_type(4))) float f32x4;

static __device__ __forceinline__ unsigned short f2bf(float f) {
    union { float f; uint32_t u; } v; v.f = f;
    uint32_t u = v.u;
    u += 0x7FFFu + ((u >> 16) & 1u);   // round-to-nearest-even
    return (unsigned short)(u >> 16);
}

// fp32 features -> bf16, one float4 per thread
__global__ void prep_features(const float* __restrict__ F, unsigned short* __restrict__ Fb) {
    int t = blockIdx.x * blockDim.x + threadIdx.x;
    float4 v = ((const float4*)F)[t];
    ushort4 o;
    o.x = f2bf(v.x); o.y = f2bf(v.y); o.z = f2bf(v.z); o.w = f2bf(v.w);
    ((ushort4*)Fb)[t] = o;
}

// Q[l][k] = 0.5*(P[idx[l,1]][k] + P[idx[l,2]][k]) as bf16; rows >= NUM_LEAVES zeroed.
__global__ void prep_q(const float* __restrict__ P, const int* __restrict__ idx,
                       unsigned short* __restrict__ Qb) {
    int t = blockIdx.x * blockDim.x + threadIdx.x;
    int l = t >> 5;
    int c = (t & 31) << 2;
    ushort4 o;
    if (l < NUM_LEAVES) {
        int i1 = idx[l * 3 + 1];
        int i2 = idx[l * 3 + 2];
        float4 a = *(const float4*)&P[(size_t)i1 * K_DIM + c];
        float4 b = *(const float4*)&P[(size_t)i2 * K_DIM + c];
        o.x = f2bf(0.5f * (a.x + b.x));
        o.y = f2bf(0.5f * (a.y + b.y));
        o.z = f2bf(0.5f * (a.z + b.z));
        o.w = f2bf(0.5f * (a.w + b.w));
    } else {
        o.x = 0; o.y = 0; o.z = 0; o.w = 0;
    }
    *(ushort4*)&Qb[(size_t)l * K_DIM + c] = o;
}

// out = Fb @ Qb^T, 128x128 block tile, full K=128 resident in LDS, 4 waves of 64x64.
// Grid is 1D with a bijective XCD-chunked, bn-major mapping: each XCD owns a
// contiguous bn-range, so Fb (2 MB) stays L2-resident per XCD and the active
// B-window is ~2 tiles (64 KB) -> staging reads become L2 hits instead of
// competing with the 328 MB write stream on the HBM fabric. Adjacent-bn blocks
// are same-XCD + temporally close, so odd-row straddled lines merge in L2
// (stores are plain, not nontemporal, to permit the merge).
__global__ __launch_bounds__(256, 2) void gemm_fq(
    const unsigned short* __restrict__ Fb,
    const unsigned short* __restrict__ Qb,
    float* __restrict__ out) {
    // 69,632 B shared pool: As/Bs (2 x 128 x 136 bf16) during GEMM,
    // reused as 128 x 132 f32 transpose buffer (67,584 B) in the epilogue.
    __shared__ __align__(16) unsigned char smem[2 * 128 * LDS_STRIDE * 2];
    unsigned short* As = (unsigned short*)smem;
    unsigned short* Bs = As + 128 * LDS_STRIDE;
    float* T = (float*)smem;

    // Bijective XCD-chunk swizzle (NWG = 5056 = 8 * 632), bn-major within chunk.
    const int lin = blockIdx.x;
    const int wg  = (lin & 7) * (NWG / 8) + (lin >> 3);
    const int bn  = wg >> 6;    // 0..78  (64 bm per bn)
    const int bm  = wg & 63;    // 0..63
    const int tid = threadIdx.x;

    // Stage both 128x128 bf16 tiles (32 KB each): 2048 16B chunks, 8 per thread.
    {
        const uint4* gA = (const uint4*)(Fb + (size_t)bm * 128 * K_DIM);
        const uint4* gB = (const uint4*)(Qb + (size_t)bn * 128 * K_DIM);
#pragma unroll
        for (int i = 0; i < 8; ++i) {
            int c = tid + i * 256;      // chunk id; element offset = c*8, row = c>>4
            int r = c >> 4;
            int c8 = (c & 15) << 3;
            uint4 va = gA[c];
            uint4 vb = gB[c];
            *(uint4*)&As[r * LDS_STRIDE + c8] = va;
            *(uint4*)&Bs[r * LDS_STRIDE + c8] = vb;
        }
    }
    __syncthreads();

    const int lane = tid & 63;
    const int w    = tid >> 6;
    const int wm   = (w >> 1) * 64;
    const int wn   = (w & 1) * 64;
    const int l15  = lane & 15;
    const int quad = lane >> 4;

    f32x4 acc[4][4] = {};

#pragma unroll
    for (int kt = 0; kt < 4; ++kt) {
        const int k0 = kt * 32 + quad * 8;
        bf16x8 af[4], bfr[4];
#pragma unroll
        for (int i = 0; i < 4; ++i) {
            af[i]  = *(const bf16x8*)&As[(wm + i * 16 + l15) * LDS_STRIDE + k0];
            bfr[i] = *(const bf16x8*)&Bs[(wn + i * 16 + l15) * LDS_STRIDE + k0];
        }
        // Swapped operands: D's reg dim walks leaf columns (contiguous in out).
#pragma unroll
        for (int mi = 0; mi < 4; ++mi)
#pragma unroll
            for (int ni = 0; ni < 4; ++ni)
                acc[mi][ni] = __builtin_amdgcn_mfma_f32_16x16x32_bf16(
                    bfr[ni], af[mi], acc[mi][ni], 0, 0, 0);
    }

    // ---- Epilogue: transpose through LDS, then long contiguous stores ----
    __syncthreads();   // all waves done reading As/Bs before overwrite

    // acc[mi][ni] covers out row n_local = wm + mi*16 + l15 (feature dim),
    // cols c_local = wn + quad*4 + ni*16 .. +3 (leaf dim, contiguous).
    {
        const int nbase = wm + l15;
        const int cb    = wn + quad * 4;
#pragma unroll
        for (int mi = 0; mi < 4; ++mi) {
            float* trow = T + (size_t)(nbase + mi * 16) * T_STRIDE;
#pragma unroll
            for (int ni = 0; ni < 4; ++ni) {
                *(f32x4*)&trow[cb + ni * 16] = acc[mi][ni];
            }
        }
    }
    __syncthreads();

    // Each wave stores rows [w*32, w*32+32): 2 rows per instruction,
    // 32 lanes x 16 B = 512 B contiguous per row.
    {
        const int half = lane >> 5;         // 0/1 -> row parity within pair
        const int cx   = (lane & 31) << 2;  // f32 col offset 0..124
        int vcols = NUM_LEAVES - bn * 128;  // valid cols in this tile (16 for bn=78)
        if (vcols > 128) vcols = 128;
        const bool ok = cx < vcols;         // whole float4 valid (10000 % 4 == 0)
        float* gbase = out + (size_t)(bm * 128) * NUM_LEAVES + (size_t)bn * 128 + cx;
        const int r0 = w * 32 + half;
#pragma unroll
        for (int it = 0; it < 16; ++it) {
            const int r = r0 + it * 2;
            f32x4 v = *(const f32x4*)&T[(size_t)r * T_STRIDE + cx];
            if (ok) {
                *(f32x4*)(gbase + (size_t)r * NUM_LEAVES) = v;   // plain: let L2 merge
            }
        }
    }
}

extern "C" void kernel_launch(void* const* d_in, const int* in_sizes, int n_in,
                              void* d_out, int out_size, void* d_ws, size_t ws_size,
                              hipStream_t stream) {
    const float* F  = (const float*)d_in[0];   // 8192*128 f32
    const float* P  = (const float*)d_in[1];   // 10101*128 f32
    const int* idx  = (const int*)d_in[2];     // 10000*3 i32
    float* out      = (float*)d_out;           // 8192*10000 f32

    unsigned short* Fb = (unsigned short*)d_ws;            // 8192*128 bf16 (2 MB)
    unsigned short* Qb = Fb + (size_t)M_DIM * K_DIM;       // 10112*128 bf16 (2.6 MB)

    prep_features<<<(M_DIM * K_DIM / 4) / 256, 256, 0, stream>>>(F, Fb);
    prep_q<<<(N_PAD * 32) / 256, 256, 0, stream>>>(P, idx, Qb);
    gemm_fq<<<NWG, 256, 0, stream>>>(Fb, Qb, out);
}

// Round 6
// 376.692 us; speedup vs baseline: 1.1947x; 1.0089x over previous
//
#include <hip/hip_runtime.h>
#include <hip/hip_bf16.h>
#include <stdint.h>

// Problem constants: features 8192x128 f32, prototypes 10101x128 f32,
// path_idx 10000x3 i32, weights [0,1,1]/2 -> out[n,l] = 0.5*(F[n].P[idx1] + F[n].P[idx2])
#define M_DIM      8192
#define K_DIM      128
#define NUM_LEAVES 10000
#define N_PAD      10112   // 79 * 128, zero-padded Q rows
#define NT         79      // N tiles of 128
#define MT         64      // M tiles of 128
#define HS         68      // shorts per row of a 64-col K-half (136 B: 2-bank rotate, conflict-free-min)
#define T_STRIDE   132     // f32 transpose stride (4-bank rotate, 8-phase minimum)

typedef __attribute__((ext_vector_type(8))) short bf16x8;
typedef __attribute__((ext_vector_type(4))) float f32x4;

static __device__ __forceinline__ unsigned short f2bf(float f) {
    union { float f; uint32_t u; } v; v.f = f;
    uint32_t u = v.u;
    u += 0x7FFFu + ((u >> 16) & 1u);   // round-to-nearest-even
    return (unsigned short)(u >> 16);
}

// fp32 features -> bf16, one float4 per thread
__global__ void prep_features(const float* __restrict__ F, unsigned short* __restrict__ Fb) {
    int t = blockIdx.x * blockDim.x + threadIdx.x;
    float4 v = ((const float4*)F)[t];
    ushort4 o;
    o.x = f2bf(v.x); o.y = f2bf(v.y); o.z = f2bf(v.z); o.w = f2bf(v.w);
    ((ushort4*)Fb)[t] = o;
}

// Q[l][k] = 0.5*(P[idx[l,1]][k] + P[idx[l,2]][k]) as bf16; rows >= NUM_LEAVES zeroed.
__global__ void prep_q(const float* __restrict__ P, const int* __restrict__ idx,
                       unsigned short* __restrict__ Qb) {
    int t = blockIdx.x * blockDim.x + threadIdx.x;
    int l = t >> 5;
    int c = (t & 31) << 2;
    ushort4 o;
    if (l < NUM_LEAVES) {
        int i1 = idx[l * 3 + 1];
        int i2 = idx[l * 3 + 2];
        float4 a = *(const float4*)&P[(size_t)i1 * K_DIM + c];
        float4 b = *(const float4*)&P[(size_t)i2 * K_DIM + c];
        o.x = f2bf(0.5f * (a.x + b.x));
        o.y = f2bf(0.5f * (a.y + b.y));
        o.z = f2bf(0.5f * (a.z + b.z));
        o.w = f2bf(0.5f * (a.w + b.w));
    } else {
        o.x = 0; o.y = 0; o.z = 0; o.w = 0;
    }
    *(ushort4*)&Qb[(size_t)l * K_DIM + c] = o;
}

// out = Fb @ Qb^T, 128x128 tile, 4 waves of 64x64. vs R2: K staged in two 64-col
// halves and the f32 transpose done in two 64-row phases, so the LDS pool is
// 34.8 KB (was 68) -> 4 blocks/CU (was 2). Theory: per-block store bursts
// (64 KB at end of life) drain at the CU's fair HBM share (~2.6 us); 2 resident
// blocks can't cover that drain with compute, 4 can. nt stores (R5: plain
// stores dirty L3 and slow the harness fill by ~28 us/iter).
__global__ __launch_bounds__(256, 4) void gemm_fq(
    const unsigned short* __restrict__ Fb,
    const unsigned short* __restrict__ Qb,
    float* __restrict__ out) {
    // Pool: staging As2/Bs2 (2 x 128 x 68 shorts = 34,816 B) reused as
    // T = 64 x 132 f32 (33,792 B) in the epilogue phases.
    __shared__ __align__(16) unsigned char smem[2 * 128 * HS * 2];
    unsigned short* As2 = (unsigned short*)smem;
    unsigned short* Bs2 = As2 + 128 * HS;
    float* T = (float*)smem;

    const int bn = blockIdx.x;   // 0..78 (fastest -> proven R2 dispatch order)
    const int bm = blockIdx.y;   // 0..63
    const int tid = threadIdx.x;

    const int lane = tid & 63;
    const int w    = tid >> 6;
    const int wm   = (w >> 1) * 64;
    const int wn   = (w & 1) * 64;
    const int l15  = lane & 15;
    const int quad = lane >> 4;

    const uint4* gA = (const uint4*)(Fb + (size_t)bm * 128 * K_DIM);
    const uint4* gB = (const uint4*)(Qb + (size_t)bn * 128 * K_DIM);

    f32x4 acc[4][4] = {};

#pragma unroll
    for (int h = 0; h < 2; ++h) {
        // ---- stage K-half h: 128 rows x 64 cols bf16 for A and B ----
        // 1024 16B chunks per matrix; chunk c -> row c>>3, uint4 q = c&7.
        // global uint4 index = row*16 + h*8 + q (K_DIM/8 = 16 uint4 per row).
#pragma unroll
        for (int i = 0; i < 4; ++i) {
            int c = tid + i * 256;
            int r = c >> 3;
            int q = c & 7;
            uint4 va = gA[r * 16 + h * 8 + q];
            uint4 vb = gB[r * 16 + h * 8 + q];
            *(uint4*)&As2[r * HS + q * 8] = va;
            *(uint4*)&Bs2[r * HS + q * 8] = vb;
        }
        __syncthreads();

        // ---- MFMA over this half's two 32-wide K-steps ----
#pragma unroll
        for (int kt = 0; kt < 2; ++kt) {
            const int k0 = kt * 32 + quad * 8;
            bf16x8 af[4], bfr[4];
#pragma unroll
            for (int i = 0; i < 4; ++i) {
                af[i]  = *(const bf16x8*)&As2[(wm + i * 16 + l15) * HS + k0];
                bfr[i] = *(const bf16x8*)&Bs2[(wn + i * 16 + l15) * HS + k0];
            }
            // Swapped operands: D's reg dim walks leaf columns (contiguous in out).
#pragma unroll
            for (int mi = 0; mi < 4; ++mi)
#pragma unroll
                for (int ni = 0; ni < 4; ++ni)
                    acc[mi][ni] = __builtin_amdgcn_mfma_f32_16x16x32_bf16(
                        bfr[ni], af[mi], acc[mi][ni], 0, 0, 0);
        }
        __syncthreads();   // done reading this half (or: before T reuse, h==1)
    }

    // ---- Epilogue: two 64-row transpose phases through T, nt stores ----
    int vcols = NUM_LEAVES - bn * 128;   // valid cols in tile (16 for bn=78)
    if (vcols > 128) vcols = 128;
    const int half = lane >> 5;          // row parity within a pair
    const int cx   = (lane & 31) << 2;   // f32 col offset 0..124
    const bool ok  = cx < vcols;         // whole float4 valid (10000 % 4 == 0)
    float* gbase = out + (size_t)bn * 128 + cx;

#pragma unroll
    for (int ph = 0; ph < 2; ++ph) {
        // Waves owning wm == ph*64 write their acc into T rows 0..63.
        if ((w >> 1) == ph) {
            const int cb = wn + quad * 4;
#pragma unroll
            for (int mi = 0; mi < 4; ++mi) {
                float* trow = T + (size_t)(mi * 16 + l15) * T_STRIDE;
#pragma unroll
                for (int ni = 0; ni < 4; ++ni)
                    *(f32x4*)&trow[cb + ni * 16] = acc[mi][ni];
            }
        }
        __syncthreads();

        // All 4 waves store the 64 rows: wave w -> T rows [w*16, w*16+16),
        // 2 rows per instruction, 512 B contiguous per row.
        const int r0 = w * 16 + half;
#pragma unroll
        for (int it = 0; it < 8; ++it) {
            const int r = r0 + it * 2;
            f32x4 v = *(const f32x4*)&T[(size_t)r * T_STRIDE + cx];
            if (ok) {
                const int grow = bm * 128 + ph * 64 + r;
                __builtin_nontemporal_store(v, (f32x4*)(gbase + (size_t)grow * NUM_LEAVES));
            }
        }
        if (ph == 0) __syncthreads();   // T readers done before phase-1 writes
    }
}

extern "C" void kernel_launch(void* const* d_in, const int* in_sizes, int n_in,
                              void* d_out, int out_size, void* d_ws, size_t ws_size,
                              hipStream_t stream) {
    const float* F  = (const float*)d_in[0];   // 8192*128 f32
    const float* P  = (const float*)d_in[1];   // 10101*128 f32
    const int* idx  = (const int*)d_in[2];     // 10000*3 i32
    float* out      = (float*)d_out;           // 8192*10000 f32

    unsigned short* Fb = (unsigned short*)d_ws;            // 8192*128 bf16 (2 MB)
    unsigned short* Qb = Fb + (size_t)M_DIM * K_DIM;       // 10112*128 bf16 (2.6 MB)

    prep_features<<<(M_DIM * K_DIM / 4) / 256, 256, 0, stream>>>(F, Fb);
    prep_q<<<(N_PAD * 32) / 256, 256, 0, stream>>>(P, idx, Qb);
    gemm_fq<<<dim3(NT, MT), 256, 0, stream>>>(Fb, Qb, out);
}

// Round 8
// 347.221 us; speedup vs baseline: 1.2961x; 1.0849x over previous
//
#include <hip/hip_runtime.h>
#include <hip/hip_bf16.h>
#include <stdint.h>

// Problem constants: features 8192x128 f32, prototypes 10101x128 f32,
// path_idx 10000x3 i32, weights [0,1,1]/2 -> out[n,l] = 0.5*(F[n].P[idx1] + F[n].P[idx2])
#define M_DIM      8192
#define K_DIM      128
#define NUM_LEAVES 10000
#define N_PAD      10112   // 79*128 zero-padded Q rows (workspace layout unchanged)
#define NTB        40      // N tiles of 256 (covers 10240 virtual cols; tail guarded)
#define MTB        64      // M tiles of 128
#define LDS_STRIDE 136     // shorts per K=128 row (+16B pad): proven rotating-bank layout
#define T_STRIDE2  260     // f32 transpose stride; 260%32==4 -> same proven rotation as 132

typedef __attribute__((ext_vector_type(8))) short bf16x8;
typedef __attribute__((ext_vector_type(4))) float f32x4;

static __device__ __forceinline__ unsigned short f2bf(float f) {
    union { float f; uint32_t u; } v; v.f = f;
    uint32_t u = v.u;
    u += 0x7FFFu + ((u >> 16) & 1u);   // round-to-nearest-even
    return (unsigned short)(u >> 16);
}

// fp32 features -> bf16, one float4 per thread
__global__ void prep_features(const float* __restrict__ F, unsigned short* __restrict__ Fb) {
    int t = blockIdx.x * blockDim.x + threadIdx.x;
    float4 v = ((const float4*)F)[t];
    ushort4 o;
    o.x = f2bf(v.x); o.y = f2bf(v.y); o.z = f2bf(v.z); o.w = f2bf(v.w);
    ((ushort4*)Fb)[t] = o;
}

// Q[l][k] = 0.5*(P[idx[l,1]][k] + P[idx[l,2]][k]) as bf16; rows >= NUM_LEAVES zeroed.
__global__ void prep_q(const float* __restrict__ P, const int* __restrict__ idx,
                       unsigned short* __restrict__ Qb) {
    int t = blockIdx.x * blockDim.x + threadIdx.x;
    int l = t >> 5;
    int c = (t & 31) << 2;
    ushort4 o;
    if (l < NUM_LEAVES) {
        int i1 = idx[l * 3 + 1];
        int i2 = idx[l * 3 + 2];
        float4 a = *(const float4*)&P[(size_t)i1 * K_DIM + c];
        float4 b = *(const float4*)&P[(size_t)i2 * K_DIM + c];
        o.x = f2bf(0.5f * (a.x + b.x));
        o.y = f2bf(0.5f * (a.y + b.y));
        o.z = f2bf(0.5f * (a.z + b.z));
        o.w = f2bf(0.5f * (a.w + b.w));
    } else {
        o.x = 0; o.y = 0; o.z = 0; o.w = 0;
    }
    *(ushort4*)&Qb[(size_t)l * K_DIM + c] = o;
}

// out = Fb @ Qb^T, 128(M) x 256(N) block tile, K=128 resident, 8 waves of 64x64.
// Extends R2's one proven lever (store run length): epilogue emits one FULL
// 256-col row (1024 B contiguous) per store instruction, halving the fraction
// of 64 B partial-line edge requests (odd rows start at 64 mod 128). Internals
// (fragment math, swapped MFMA, LDS strides mod 32, nt stores) are R2-proven.
// 104 KB LDS -> 1 block/CU; s_endpgm retires with stores in flight, so the
// write drain overlaps the next block's staging on the same CU.
// (R6 submission had a staging-index bug -- half-staged LDS; fixed here with
// the R2-proven r=c>>4/q=c&15 math scaled to 512 threads.)
__global__ __launch_bounds__(512, 1) void gemm_fq(
    const unsigned short* __restrict__ Fb,
    const unsigned short* __restrict__ Qb,
    float* __restrict__ out) {
    // Pool: As 128x136 + Bs 256x136 shorts = 104,448 B during GEMM,
    // reused as T = 64 x 260 f32 (66,560 B) in the two epilogue phases.
    __shared__ __align__(16) unsigned char smem[(128 + 256) * LDS_STRIDE * 2];
    unsigned short* As = (unsigned short*)smem;
    unsigned short* Bs = As + 128 * LDS_STRIDE;
    float* T = (float*)smem;

    const int bn = blockIdx.x;   // 0..39 (fastest: same dispatch style as R2)
    const int bm = blockIdx.y;   // 0..63
    const int tid = threadIdx.x;

    // ---- stage A: 128 rows x 16 uint4 = 2048 chunks, 4 per thread ----
    {
        const uint4* gA = (const uint4*)(Fb + (size_t)bm * 128 * K_DIM);
#pragma unroll
        for (int i = 0; i < 4; ++i) {
            int c = tid + i * 512;      // 0..2047
            int r = c >> 4;             // 0..127
            int q = c & 15;             // 0..15 (uint4 within row)
            uint4 v = gA[c];            // gA[r*16 + q] == gA[c]
            *(uint4*)&As[r * LDS_STRIDE + q * 8] = v;
        }
    }
    // ---- stage B: 256 rows x 16 uint4 = 4096 chunks, 8 per thread; guard rows >= N_PAD ----
    {
        const uint4* gQ = (const uint4*)Qb;
#pragma unroll
        for (int i = 0; i < 8; ++i) {
            int c = tid + i * 512;      // 0..4095
            int r = c >> 4;             // 0..255
            int q = c & 15;
            int gr = bn * 256 + r;
            uint4 v = make_uint4(0u, 0u, 0u, 0u);
            if (gr < N_PAD) v = gQ[(size_t)gr * 16 + q];
            *(uint4*)&Bs[r * LDS_STRIDE + q * 8] = v;
        }
    }
    __syncthreads();

    const int lane = tid & 63;
    const int w    = tid >> 6;        // 0..7
    const int wm   = (w >> 2) * 64;   // 0,64       (2 M-waves)
    const int wn   = (w & 3) * 64;    // 0..192     (4 N-waves)
    const int l15  = lane & 15;
    const int quad = lane >> 4;

    f32x4 acc[4][4] = {};

#pragma unroll
    for (int kt = 0; kt < 4; ++kt) {
        const int k0 = kt * 32 + quad * 8;
        bf16x8 af[4], bfr[4];
#pragma unroll
        for (int i = 0; i < 4; ++i) {
            af[i]  = *(const bf16x8*)&As[(wm + i * 16 + l15) * LDS_STRIDE + k0];
            bfr[i] = *(const bf16x8*)&Bs[(wn + i * 16 + l15) * LDS_STRIDE + k0];
        }
        // Swapped operands: D's reg dim walks leaf columns (contiguous in out).
#pragma unroll
        for (int mi = 0; mi < 4; ++mi)
#pragma unroll
            for (int ni = 0; ni < 4; ++ni)
                acc[mi][ni] = __builtin_amdgcn_mfma_f32_16x16x32_bf16(
                    bfr[ni], af[mi], acc[mi][ni], 0, 0, 0);
    }
    __syncthreads();   // all waves done with As/Bs before T reuse

    // ---- Epilogue: two 64-row transpose phases; 1 full row (1 KB) per store ----
    const int cx   = lane << 2;              // f32 col in tile, 0..252
    const int ccol = bn * 256 + cx;
    const bool ok  = ccol < NUM_LEAVES;      // whole float4 valid (10000 % 4 == 0)
    float* gbase = out + ccol;

#pragma unroll
    for (int ph = 0; ph < 2; ++ph) {
        // Waves of M-half ph dump acc[][]: T rows mi*16+l15 (0..63), cols wn+quad*4+ni*16.
        if ((w >> 2) == ph) {
            const int cb = wn + quad * 4;
#pragma unroll
            for (int mi = 0; mi < 4; ++mi) {
                float* trow = T + (size_t)(mi * 16 + l15) * T_STRIDE2;
#pragma unroll
                for (int ni = 0; ni < 4; ++ni)
                    *(f32x4*)&trow[cb + ni * 16] = acc[mi][ni];
            }
        }
        __syncthreads();

        // 8 waves x 8 rows: one instruction stores a full 256-col row (1024 B).
#pragma unroll
        for (int it = 0; it < 8; ++it) {
            const int r = w * 8 + it;
            f32x4 v = *(const f32x4*)&T[(size_t)r * T_STRIDE2 + cx];
            if (ok) {
                const int grow = bm * 128 + ph * 64 + r;
                __builtin_nontemporal_store(v, (f32x4*)(gbase + (size_t)grow * NUM_LEAVES));
            }
        }
        if (ph == 0) __syncthreads();   // T readers done before phase-1 dump
    }
}

extern "C" void kernel_launch(void* const* d_in, const int* in_sizes, int n_in,
                              void* d_out, int out_size, void* d_ws, size_t ws_size,
                              hipStream_t stream) {
    const float* F  = (const float*)d_in[0];   // 8192*128 f32
    const float* P  = (const float*)d_in[1];   // 10101*128 f32
    const int* idx  = (const int*)d_in[2];     // 10000*3 i32
    float* out      = (float*)d_out;           // 8192*10000 f32

    unsigned short* Fb = (unsigned short*)d_ws;            // 8192*128 bf16 (2 MB)
    unsigned short* Qb = Fb + (size_t)M_DIM * K_DIM;       // 10112*128 bf16 (2.6 MB)

    prep_features<<<(M_DIM * K_DIM / 4) / 256, 256, 0, stream>>>(F, Fb);
    prep_q<<<(N_PAD * 32) / 256, 256, 0, stream>>>(P, idx, Qb);
    gemm_fq<<<dim3(NTB, MTB), 512, 0, stream>>>(Fb, Qb, out);
}

// Round 9
// 339.050 us; speedup vs baseline: 1.3274x; 1.0241x over previous
//
#include <hip/hip_runtime.h>
#include <hip/hip_bf16.h>
#include <stdint.h>

// Problem constants: features 8192x128 f32, prototypes 10101x128 f32,
// path_idx 10000x3 i32, weights [0,1,1]/2 -> out[n,l] = 0.5*(F[n].P[idx1] + F[n].P[idx2])
#define M_DIM      8192
#define K_DIM      128
#define NUM_LEAVES 10000
#define N_PAD      10112   // 79 * 128, zero-padded Q rows
#define NT         79      // N tiles of 128
#define MT         64      // M tiles of 128
#define LDS_STRIDE 136     // 128 + 8 bf16 pad (16B) -> b128 reads land on rotating banks
#define T_STRIDE   132     // f32 transpose-staging stride (conflict-minimal b128)

typedef __attribute__((ext_vector_type(8))) short bf16x8;
typedef __attribute__((ext_vector_type(4))) float f32x4;

static __device__ __forceinline__ unsigned short f2bf(float f) {
    union { float f; uint32_t u; } v; v.f = f;
    uint32_t u = v.u;
    u += 0x7FFFu + ((u >> 16) & 1u);   // round-to-nearest-even
    return (unsigned short)(u >> 16);
}

// fp32 features -> bf16, one float4 per thread
__global__ void prep_features(const float* __restrict__ F, unsigned short* __restrict__ Fb) {
    int t = blockIdx.x * blockDim.x + threadIdx.x;
    float4 v = ((const float4*)F)[t];
    ushort4 o;
    o.x = f2bf(v.x); o.y = f2bf(v.y); o.z = f2bf(v.z); o.w = f2bf(v.w);
    ((ushort4*)Fb)[t] = o;
}

// Q[l][k] = 0.5*(P[idx[l,1]][k] + P[idx[l,2]][k]) as bf16; rows >= NUM_LEAVES zeroed.
__global__ void prep_q(const float* __restrict__ P, const int* __restrict__ idx,
                       unsigned short* __restrict__ Qb) {
    int t = blockIdx.x * blockDim.x + threadIdx.x;
    int l = t >> 5;
    int c = (t & 31) << 2;
    ushort4 o;
    if (l < NUM_LEAVES) {
        int i1 = idx[l * 3 + 1];
        int i2 = idx[l * 3 + 2];
        float4 a = *(const float4*)&P[(size_t)i1 * K_DIM + c];
        float4 b = *(const float4*)&P[(size_t)i2 * K_DIM + c];
        o.x = f2bf(0.5f * (a.x + b.x));
        o.y = f2bf(0.5f * (a.y + b.y));
        o.z = f2bf(0.5f * (a.z + b.z));
        o.w = f2bf(0.5f * (a.w + b.w));
    } else {
        o.x = 0; o.y = 0; o.z = 0; o.w = 0;
    }
    *(ushort4*)&Qb[(size_t)l * K_DIM + c] = o;
}

// out = Fb @ Qb^T, 128x128 block tile, full K=128 resident in LDS, 4 waves of 64x64.
// Identical to the R2 kernel (measured best: 338.5 us) except the epilogue
// readback: LDS reads are batched into registers, then 8 independent nt stores
// are issued back-to-back -> per-wave outstanding-store depth ~8 instead of ~1-2.
// Theory: the write pipe is MLP-starved (fill hits 6.3 TB/s at 10% occupancy via
// long independent store chains); deeper per-wave store issue should lift the
// gemm's effective 2.6 TB/s toward the streaming ceiling.
__global__ __launch_bounds__(256, 2) void gemm_fq(
    const unsigned short* __restrict__ Fb,
    const unsigned short* __restrict__ Qb,
    float* __restrict__ out) {
    // 69,632 B shared pool: As/Bs (2 x 128 x 136 bf16) during GEMM,
    // reused as 128 x 132 f32 transpose buffer (67,584 B) in the epilogue.
    __shared__ __align__(16) unsigned char smem[2 * 128 * LDS_STRIDE * 2];
    unsigned short* As = (unsigned short*)smem;
    unsigned short* Bs = As + 128 * LDS_STRIDE;
    float* T = (float*)smem;

    const int bn = blockIdx.x;   // 0..78
    const int bm = blockIdx.y;   // 0..63
    const int tid = threadIdx.x;

    // Stage both 128x128 bf16 tiles (32 KB each): 2048 16B chunks, 8 per thread.
    {
        const uint4* gA = (const uint4*)(Fb + (size_t)bm * 128 * K_DIM);
        const uint4* gB = (const uint4*)(Qb + (size_t)bn * 128 * K_DIM);
#pragma unroll
        for (int i = 0; i < 8; ++i) {
            int c = tid + i * 256;      // chunk id; element offset = c*8, row = c>>4
            int r = c >> 4;
            int c8 = (c & 15) << 3;
            uint4 va = gA[c];
            uint4 vb = gB[c];
            *(uint4*)&As[r * LDS_STRIDE + c8] = va;
            *(uint4*)&Bs[r * LDS_STRIDE + c8] = vb;
        }
    }
    __syncthreads();

    const int lane = tid & 63;
    const int w    = tid >> 6;
    const int wm   = (w >> 1) * 64;
    const int wn   = (w & 1) * 64;
    const int l15  = lane & 15;
    const int quad = lane >> 4;

    f32x4 acc[4][4] = {};

#pragma unroll
    for (int kt = 0; kt < 4; ++kt) {
        const int k0 = kt * 32 + quad * 8;
        bf16x8 af[4], bfr[4];
#pragma unroll
        for (int i = 0; i < 4; ++i) {
            af[i]  = *(const bf16x8*)&As[(wm + i * 16 + l15) * LDS_STRIDE + k0];
            bfr[i] = *(const bf16x8*)&Bs[(wn + i * 16 + l15) * LDS_STRIDE + k0];
        }
        // Swapped operands: D's reg dim walks leaf columns (contiguous in out).
#pragma unroll
        for (int mi = 0; mi < 4; ++mi)
#pragma unroll
            for (int ni = 0; ni < 4; ++ni)
                acc[mi][ni] = __builtin_amdgcn_mfma_f32_16x16x32_bf16(
                    bfr[ni], af[mi], acc[mi][ni], 0, 0, 0);
    }

    // ---- Epilogue: transpose through LDS, then burst contiguous stores ----
    __syncthreads();   // all waves done reading As/Bs before overwrite

    // acc[mi][ni] covers out row n_local = wm + mi*16 + l15 (feature dim),
    // cols c_local = wn + quad*4 + ni*16 .. +3 (leaf dim, contiguous).
    {
        const int nbase = wm + l15;
        const int cb    = wn + quad * 4;
#pragma unroll
        for (int mi = 0; mi < 4; ++mi) {
            float* trow = T + (size_t)(nbase + mi * 16) * T_STRIDE;
#pragma unroll
            for (int ni = 0; ni < 4; ++ni) {
                *(f32x4*)&trow[cb + ni * 16] = acc[mi][ni];
            }
        }
    }
    __syncthreads();

    // Each wave stores rows [w*32, w*32+32): 2 rows per instruction,
    // 32 lanes x 16 B = 512 B contiguous per row. Readback is batched:
    // 8 ds_read_b128 -> regs, then 8 independent nt stores back-to-back.
    {
        const int half = lane >> 5;         // 0/1 -> row parity within pair
        const int cx   = (lane & 31) << 2;  // f32 col offset 0..124
        int vcols = NUM_LEAVES - bn * 128;  // valid cols in this tile (16 for bn=78)
        if (vcols > 128) vcols = 128;
        const bool ok = cx < vcols;         // whole float4 valid (10000 % 4 == 0)
        float* gbase = out + (size_t)(bm * 128) * NUM_LEAVES + (size_t)bn * 128 + cx;
        const int r0 = w * 32 + half;

        f32x4 vbuf[8];
#pragma unroll
        for (int b = 0; b < 2; ++b) {
            // batch-load 8 rows from LDS into registers
#pragma unroll
            for (int it = 0; it < 8; ++it) {
                const int r = r0 + (b * 8 + it) * 2;
                vbuf[it] = *(const f32x4*)&T[(size_t)r * T_STRIDE + cx];
            }
            __builtin_amdgcn_sched_barrier(0);   // keep loads clustered before stores
            // burst 8 independent stores (no intervening LDS waits)
            if (ok) {
#pragma unroll
                for (int it = 0; it < 8; ++it) {
                    const int r = r0 + (b * 8 + it) * 2;
                    __builtin_nontemporal_store(vbuf[it], (f32x4*)(gbase + (size_t)r * NUM_LEAVES));
                }
            }
        }
    }
}

extern "C" void kernel_launch(void* const* d_in, const int* in_sizes, int n_in,
                              void* d_out, int out_size, void* d_ws, size_t ws_size,
                              hipStream_t stream) {
    const float* F  = (const float*)d_in[0];   // 8192*128 f32
    const float* P  = (const float*)d_in[1];   // 10101*128 f32
    const int* idx  = (const int*)d_in[2];     // 10000*3 i32
    float* out      = (float*)d_out;           // 8192*10000 f32

    unsigned short* Fb = (unsigned short*)d_ws;            // 8192*128 bf16 (2 MB)
    unsigned short* Qb = Fb + (size_t)M_DIM * K_DIM;       // 10112*128 bf16 (2.6 MB)

    prep_features<<<(M_DIM * K_DIM / 4) / 256, 256, 0, stream>>>(F, Fb);
    prep_q<<<(N_PAD * 32) / 256, 256, 0, stream>>>(P, idx, Qb);
    gemm_fq<<<dim3(NT, MT), 256, 0, stream>>>(Fb, Qb, out);
}